// Round 1
// baseline (1759.753 us; speedup 1.0000x reference)
//
#include <hip/hip_runtime.h>
#include <math.h>

#define HD 64
#define EPS 1e-5f

__device__ __forceinline__ float atomAddF(float* p, float v) {
    return unsafeAtomicAdd(p, v);   // native global_atomic_add_f32 on gfx950
}

// deg[i]=1.0 (self loop) ; zero bn-stats accumulators (256 floats)
__global__ void k_init(float* deg, float* stats, int n) {
    int i = blockIdx.x * blockDim.x + threadIdx.x;
    if (i < n) deg[i] = 1.0f;
    if (i < 256) stats[i] = 0.0f;
}

__global__ void k_deg(const int* __restrict__ dst, float* deg, int e) {
    int i = blockIdx.x * blockDim.x + threadIdx.x;
    if (i < e) atomAddF(&deg[dst[i]], 1.0f);
}

__global__ void k_dinv(float* deg, int n) {
    int i = blockIdx.x * blockDim.x + threadIdx.x;
    if (i < n) deg[i] = rsqrtf(deg[i]);
}

// hs[n][c] = dinv[n] * sum_k x[n][k]*W0[k][c]  -> writes A (gather src) and B (accumulator init = self loop)
__global__ __launch_bounds__(256) void k_lin0(const float* __restrict__ x,
        const float* __restrict__ W0, const float* __restrict__ dinv,
        float* __restrict__ A, float* __restrict__ B, int n_nodes) {
    __shared__ float w[4 * HD];
    int t = threadIdx.x;
    w[t] = W0[t];                       // 256 == 4*64
    __syncthreads();
    int n = blockIdx.x * 4 + (t >> 6);
    int c = t & 63;
    if (n >= n_nodes) return;
    float x0 = x[n * 4 + 0], x1 = x[n * 4 + 1], x2 = x[n * 4 + 2], x3 = x[n * 4 + 3];
    float v = x0 * w[c] + x1 * w[64 + c] + x2 * w[128 + c] + x3 * w[192 + c];
    v *= dinv[n];
    A[n * 64 + c] = v;
    B[n * 64 + c] = v;
}

// edge-parallel scatter: B[dst][c] += A[src][c]
__global__ __launch_bounds__(256) void k_scatter(const int* __restrict__ src,
        const int* __restrict__ dst, const float* __restrict__ A,
        float* __restrict__ B, int e) {
    int i = blockIdx.x * 256 + threadIdx.x;     // e*64 <= 204.8M < 2^31
    int eg = i >> 6;
    int c = i & 63;
    if (eg >= e) return;
    float v = A[(src[eg] << 6) + c];
    atomAddF(&B[(dst[eg] << 6) + c], v);
}

// t[n][c] = dinv[n]*B[n][c] + bias[c]; accumulate per-channel sum & sumsq
__global__ __launch_bounds__(256) void k_bn_stats(const float* __restrict__ B,
        const float* __restrict__ dinv, const float* __restrict__ bias,
        float* __restrict__ stats, int n_nodes) {
    int t = threadIdx.x;
    int c = t & 63, wv = t >> 6;
    float bc = bias[c];
    float s = 0.f, s2 = 0.f;
    for (int n = blockIdx.x * 4 + wv; n < n_nodes; n += gridDim.x * 4) {
        float v = dinv[n] * B[n * 64 + c] + bc;
        s += v;
        s2 += v * v;
    }
    __shared__ float ls[4][64], ls2[4][64];
    ls[wv][c] = s;
    ls2[wv][c] = s2;
    __syncthreads();
    if (t < 64) {
        float a = ls[0][t] + ls[1][t] + ls[2][t] + ls[3][t];
        float a2 = ls2[0][t] + ls2[1][t] + ls2[2][t] + ls2[3][t];
        atomAddF(&stats[t], a);
        atomAddF(&stats[64 + t], a2);
    }
}

// A[n][c] = relu( g*(t-mu)*rsqrt(var+eps) + be ),  t = dinv[n]*B[n][c] + bias[c]
__global__ __launch_bounds__(256) void k_bn_apply(const float* __restrict__ B,
        const float* __restrict__ dinv, const float* __restrict__ bias,
        const float* __restrict__ stats, const float* __restrict__ g,
        const float* __restrict__ be, float* __restrict__ A, int n_nodes) {
    int i = blockIdx.x * 256 + threadIdx.x;
    if (i >= n_nodes * 64) return;
    int n = i >> 6, c = i & 63;
    float inv_n = 1.0f / (float)n_nodes;
    float mu = stats[c] * inv_n;
    float var = stats[64 + c] * inv_n - mu * mu;
    float t = dinv[n] * B[i] + bias[c];
    float y = g[c] * (t - mu) * rsqrtf(var + EPS) + be[c];
    A[i] = fmaxf(y, 0.f);
}

// in-place: A <- dinv[n] * (A @ W1); B <- same (accumulator init). rows staged to LDS first.
__global__ __launch_bounds__(256) void k_lin1(const float* __restrict__ W,
        const float* __restrict__ dinv, float* __restrict__ A,
        float* __restrict__ B, int n_nodes) {
    __shared__ float w[HD * HD];
    __shared__ float rows[4][HD];
    int t = threadIdx.x;
    for (int i = t; i < HD * HD; i += 256) w[i] = W[i];
    int wv = t >> 6, c = t & 63;
    int ngroups = (n_nodes + 3) >> 2;
    for (int gidx = blockIdx.x; gidx < ngroups; gidx += gridDim.x) {
        __syncthreads();                       // rows reuse + first-iter w barrier
        int n = gidx * 4 + wv;
        float rv = (n < n_nodes) ? A[n * 64 + c] : 0.f;
        rows[wv][c] = rv;
        __syncthreads();
        if (n < n_nodes) {
            float acc = 0.f;
            #pragma unroll
            for (int k = 0; k < HD; k++) acc = fmaf(rows[wv][k], w[k * 64 + c], acc);
            acc *= dinv[n];
            A[n * 64 + c] = acc;
            B[n * 64 + c] = acc;
        }
    }
}

// fused MLP head: out = sigmoid(relu(relu(h@Wm0+bm0)@Wm1+bm1)@Wm2+bm2)
__global__ __launch_bounds__(64) void k_mlp(const float* __restrict__ A,
        const float* __restrict__ Wm0, const float* __restrict__ bm0,
        const float* __restrict__ Wm1, const float* __restrict__ bm1,
        const float* __restrict__ Wm2, const float* __restrict__ bm2,
        float* __restrict__ out, int n_nodes) {
    __shared__ float rows[64][65];             // padded: conflict-free column reads
    int t = threadIdx.x;
    int nbase = blockIdx.x * 64;
    #pragma unroll 4
    for (int r = 0; r < 64; r++) {
        int nn = nbase + r;
        rows[r][t] = (nn < n_nodes) ? A[nn * 64 + t] : 0.f;
    }
    __syncthreads();
    int n = nbase + t;
    if (n >= n_nodes) return;

    float a1[64];
    #pragma unroll
    for (int cc = 0; cc < 4; ++cc) {           // 16-wide chunks, static acc indexing
        float acc[16];
        #pragma unroll
        for (int j = 0; j < 16; ++j) acc[j] = bm0[cc * 16 + j];
        for (int k = 0; k < 64; ++k) {
            float hv = rows[t][k];
            #pragma unroll
            for (int j = 0; j < 16; ++j)
                acc[j] = fmaf(hv, Wm0[k * 64 + cc * 16 + j], acc[j]);  // wave-uniform -> s_load
        }
        #pragma unroll
        for (int j = 0; j < 16; ++j) a1[cc * 16 + j] = fmaxf(acc[j], 0.f);
    }
    // park a1 in own LDS row (private; no barrier needed) so m1 k-loop can stay rolled
    #pragma unroll
    for (int k = 0; k < 64; ++k) rows[t][k] = a1[k];

    float a2[32];
    #pragma unroll
    for (int cc = 0; cc < 2; ++cc) {
        float acc[16];
        #pragma unroll
        for (int j = 0; j < 16; ++j) acc[j] = bm1[cc * 16 + j];
        for (int k = 0; k < 64; ++k) {
            float hv = rows[t][k];
            #pragma unroll
            for (int j = 0; j < 16; ++j)
                acc[j] = fmaf(hv, Wm1[k * 32 + cc * 16 + j], acc[j]);
        }
        #pragma unroll
        for (int j = 0; j < 16; ++j) a2[cc * 16 + j] = fmaxf(acc[j], 0.f);
    }
    float z = bm2[0];
    #pragma unroll
    for (int k = 0; k < 32; ++k) z = fmaf(a2[k], Wm2[k], z);
    out[n] = 1.0f / (1.0f + __expf(-z));
}

extern "C" void kernel_launch(void* const* d_in, const int* in_sizes, int n_in,
                              void* d_out, int out_size, void* d_ws, size_t ws_size,
                              hipStream_t stream) {
    const float* x   = (const float*)d_in[0];
    const int*   src = (const int*)d_in[1];
    const int*   dst = (const int*)d_in[2];
    const float* W0  = (const float*)d_in[3];
    const float* b0  = (const float*)d_in[4];
    const float* W1  = (const float*)d_in[5];
    const float* b1  = (const float*)d_in[6];
    const float* g0  = (const float*)d_in[7];
    const float* be0 = (const float*)d_in[8];
    const float* g1  = (const float*)d_in[9];
    const float* be1 = (const float*)d_in[10];
    const float* Wm0 = (const float*)d_in[11];
    const float* bm0 = (const float*)d_in[12];
    const float* Wm1 = (const float*)d_in[13];
    const float* bm1 = (const float*)d_in[14];
    const float* Wm2 = (const float*)d_in[15];
    const float* bm2 = (const float*)d_in[16];

    int n = in_sizes[0] / 4;
    int e = in_sizes[1];
    float* out = (float*)d_out;

    char* ws = (char*)d_ws;
    auto alignup = [](size_t v) { return (v + 255) & ~(size_t)255; };
    size_t o = 0;
    float* deg   = (float*)(ws + o); o += alignup((size_t)n * 4);
    float* stats = (float*)(ws + o); o += alignup(256 * 4);
    float* A     = (float*)(ws + o); o += alignup((size_t)n * 64 * 4);
    float* B     = (float*)(ws + o);
    float* dinv  = deg;                        // in-place rsqrt

    int gN   = (n + 255) / 256;
    int gE   = (e + 255) / 256;
    int gN4  = (n + 3) / 4;
    int gNH  = (n * 64 + 255) / 256;           // n*64 = 6.4M < 2^31
    int gEC  = (int)(((long long)e * 64 + 255) / 256);
    int gMLP = (n + 63) / 64;

    k_init<<<gN, 256, 0, stream>>>(deg, stats, n);
    k_deg<<<gE, 256, 0, stream>>>(dst, deg, e);
    k_dinv<<<gN, 256, 0, stream>>>(deg, n);

    // ---- layer 1 ----
    k_lin0<<<gN4, 256, 0, stream>>>(x, W0, dinv, A, B, n);
    k_scatter<<<gEC, 256, 0, stream>>>(src, dst, A, B, e);
    k_bn_stats<<<1024, 256, 0, stream>>>(B, dinv, b0, stats, n);
    k_bn_apply<<<gNH, 256, 0, stream>>>(B, dinv, b0, stats, g0, be0, A, n);

    // ---- layer 2 ----
    k_lin1<<<2048, 256, 0, stream>>>(W1, dinv, A, B, n);
    k_scatter<<<gEC, 256, 0, stream>>>(src, dst, A, B, e);
    k_bn_stats<<<1024, 256, 0, stream>>>(B, dinv, b1, stats + 128, n);
    k_bn_apply<<<gNH, 256, 0, stream>>>(B, dinv, b1, stats + 128, g1, be1, A, n);

    // ---- MLP head ----
    k_mlp<<<gMLP, 64, 0, stream>>>(A, Wm0, bm0, Wm1, bm1, Wm2, bm2, out, n);
}

// Round 2
// 817.576 us; speedup vs baseline: 2.1524x; 2.1524x over previous
//
#include <hip/hip_runtime.h>
#include <math.h>

#define HD 64
#define EPS 1e-5f
#define SCAN_TILE 1024

__device__ __forceinline__ float atomAddF(float* p, float v) {
    return unsafeAtomicAdd(p, v);   // native global_atomic_add_f32 on gfx950
}

// ---------- CSR build ----------
__global__ void k_hist(const int* __restrict__ dst, int* __restrict__ cnt, int e) {
    int i = blockIdx.x * blockDim.x + threadIdx.x;
    if (i < e) atomicAdd(&cnt[dst[i]], 1);
}

// block-level exclusive scan of 1024 counts (256 thr x 4), partials in row_ptr
__global__ __launch_bounds__(256) void k_scan1(const int* __restrict__ cnt,
        int* __restrict__ row_ptr, int* __restrict__ bsum, int n) {
    __shared__ int sc[256];
    int t = threadIdx.x;
    int base = blockIdx.x * SCAN_TILE + t * 4;
    int v0 = (base + 0 < n) ? cnt[base + 0] : 0;
    int v1 = (base + 1 < n) ? cnt[base + 1] : 0;
    int v2 = (base + 2 < n) ? cnt[base + 2] : 0;
    int v3 = (base + 3 < n) ? cnt[base + 3] : 0;
    int tsum = v0 + v1 + v2 + v3;
    sc[t] = tsum;
    __syncthreads();
    int acc = tsum;
    for (int off = 1; off < 256; off <<= 1) {
        int x = (t >= off) ? sc[t - off] : 0;
        __syncthreads();
        acc += x;
        sc[t] = acc;
        __syncthreads();
    }
    int excl = acc - tsum;
    if (base + 0 < n) row_ptr[base + 0] = excl;
    if (base + 1 < n) row_ptr[base + 1] = excl + v0;
    if (base + 2 < n) row_ptr[base + 2] = excl + v0 + v1;
    if (base + 3 < n) row_ptr[base + 3] = excl + v0 + v1 + v2;
    if (t == 255) bsum[blockIdx.x] = acc;
}

__global__ __launch_bounds__(128) void k_scan2(const int* __restrict__ bsum,
        int* __restrict__ boff, int nb) {
    __shared__ int sc[128];
    int t = threadIdx.x;
    int v = (t < nb) ? bsum[t] : 0;
    sc[t] = v;
    __syncthreads();
    int acc = v;
    for (int off = 1; off < 128; off <<= 1) {
        int x = (t >= off) ? sc[t - off] : 0;
        __syncthreads();
        acc += x;
        sc[t] = acc;
        __syncthreads();
    }
    if (t < nb) boff[t] = acc - v;
}

// finalize row_ptr (+block offset), init cursor, row_ptr[n]=e
__global__ void k_scan3(int* __restrict__ row_ptr, int* __restrict__ cursor,
        const int* __restrict__ boff, int n, int e) {
    int i = blockIdx.x * blockDim.x + threadIdx.x;
    if (i < n) {
        int r = row_ptr[i] + boff[i >> 10];
        row_ptr[i] = r;
        cursor[i] = r;
    }
    if (i == 0) row_ptr[n] = e;
}

__global__ void k_dinv(const int* __restrict__ cnt, float* __restrict__ dinv, int n) {
    int i = blockIdx.x * blockDim.x + threadIdx.x;
    if (i < n) dinv[i] = rsqrtf((float)(cnt[i] + 1));   // +1 = self loop
}

__global__ void k_fill(const int* __restrict__ src, const int* __restrict__ dst,
        int* __restrict__ cursor, int* __restrict__ csr, int e) {
    int i = blockIdx.x * blockDim.x + threadIdx.x;
    if (i < e) {
        int pos = atomicAdd(&cursor[dst[i]], 1);
        csr[pos] = src[i];
    }
}

// ---------- layer compute ----------
// A[n][c] = dinv[n] * sum_k x[n][k]*W0[k][c]
__global__ __launch_bounds__(256) void k_lin0(const float* __restrict__ x,
        const float* __restrict__ W0, const float* __restrict__ dinv,
        float* __restrict__ A, int n_nodes) {
    __shared__ float w[4 * HD];
    int t = threadIdx.x;
    w[t] = W0[t];
    __syncthreads();
    int n = blockIdx.x * 4 + (t >> 6);
    int c = t & 63;
    if (n >= n_nodes) return;
    float x0 = x[n * 4 + 0], x1 = x[n * 4 + 1], x2 = x[n * 4 + 2], x3 = x[n * 4 + 3];
    float v = x0 * w[c] + x1 * w[64 + c] + x2 * w[128 + c] + x3 * w[192 + c];
    A[n * 64 + c] = v * dinv[n];
}

// CSR gather-aggregate: B[n][c] = dinv[n]*(A[n][c] + sum_{e in-edges} A[src][c]) + bias[c]
// also accumulates per-channel sum/sumsq into stats[0:64]/stats[64:128]
__global__ __launch_bounds__(256) void k_aggr(const int* __restrict__ row_ptr,
        const int* __restrict__ csr, const float* __restrict__ A,
        const float* __restrict__ dinv, const float* __restrict__ bias,
        float* __restrict__ B, float* __restrict__ stats, int n_nodes) {
    int t = threadIdx.x;
    int c = t & 63, wv = t >> 6;
    float bc = bias[c];
    float s = 0.f, s2 = 0.f;
    for (int n = blockIdx.x * 4 + wv; n < n_nodes; n += gridDim.x * 4) {
        int beg = row_ptr[n], end = row_ptr[n + 1];
        float acc = A[(n << 6) + c];           // self loop term
        int j = beg;
        for (; j + 3 < end; j += 4) {
            int s0 = csr[j], s1 = csr[j + 1], s2i = csr[j + 2], s3 = csr[j + 3];
            float a0 = A[(s0 << 6) + c];
            float a1 = A[(s1 << 6) + c];
            float a2 = A[(s2i << 6) + c];
            float a3 = A[(s3 << 6) + c];
            acc += a0 + a1 + a2 + a3;
        }
        for (; j < end; ++j) acc += A[(csr[j] << 6) + c];
        float v = dinv[n] * acc + bc;
        B[(n << 6) + c] = v;
        s += v;
        s2 += v * v;
    }
    __shared__ float ls[4][64], ls2[4][64];
    ls[wv][c] = s;
    ls2[wv][c] = s2;
    __syncthreads();
    if (t < 64) {
        float a = ls[0][t] + ls[1][t] + ls[2][t] + ls[3][t];
        float a2 = ls2[0][t] + ls2[1][t] + ls2[2][t] + ls2[3][t];
        atomAddF(&stats[t], a);
        atomAddF(&stats[64 + t], a2);
    }
}

// A <- dinv[n] * (relu(bn(B)) @ W1)     (BN0+ReLU fused into the row staging)
__global__ __launch_bounds__(256) void k_lin1(const float* __restrict__ B,
        const float* __restrict__ W, const float* __restrict__ dinv,
        const float* __restrict__ stats, const float* __restrict__ g,
        const float* __restrict__ be, float* __restrict__ A, int n_nodes) {
    __shared__ float w[HD * HD];
    __shared__ float rows[4][HD];
    int t = threadIdx.x;
    for (int i = t; i < HD * HD; i += 256) w[i] = W[i];
    int wv = t >> 6, c = t & 63;
    float inv_n = 1.0f / (float)n_nodes;
    float mu = stats[c] * inv_n;
    float var = stats[64 + c] * inv_n - mu * mu;
    float sc = g[c] * rsqrtf(var + EPS);
    float sh = be[c] - mu * sc;
    int ngroups = (n_nodes + 3) >> 2;
    for (int gidx = blockIdx.x; gidx < ngroups; gidx += gridDim.x) {
        __syncthreads();
        int n = gidx * 4 + wv;
        float rv = (n < n_nodes) ? fmaxf(sc * B[(n << 6) + c] + sh, 0.f) : 0.f;
        rows[wv][c] = rv;
        __syncthreads();
        if (n < n_nodes) {
            float acc = 0.f;
            #pragma unroll
            for (int k = 0; k < HD; k++) acc = fmaf(rows[wv][k], w[k * 64 + c], acc);
            A[(n << 6) + c] = acc * dinv[n];
        }
    }
}

// fused: h = relu(bn1(B)); out = sigmoid(relu(relu(h@Wm0+bm0)@Wm1+bm1)@Wm2+bm2)
__global__ __launch_bounds__(64) void k_mlp(const float* __restrict__ B,
        const float* __restrict__ stats, const float* __restrict__ g,
        const float* __restrict__ be,
        const float* __restrict__ Wm0, const float* __restrict__ bm0,
        const float* __restrict__ Wm1, const float* __restrict__ bm1,
        const float* __restrict__ Wm2, const float* __restrict__ bm2,
        float* __restrict__ out, int n_nodes) {
    __shared__ float rows[64][65];
    int t = threadIdx.x;
    float inv_n = 1.0f / (float)n_nodes;
    float mu = stats[t] * inv_n;
    float var = stats[64 + t] * inv_n - mu * mu;
    float sc = g[t] * rsqrtf(var + EPS);
    float sh = be[t] - mu * sc;
    int nbase = blockIdx.x * 64;
    #pragma unroll 4
    for (int r = 0; r < 64; r++) {
        int nn = nbase + r;
        rows[r][t] = (nn < n_nodes) ? fmaxf(sc * B[(nn << 6) + t] + sh, 0.f) : 0.f;
    }
    __syncthreads();
    int n = nbase + t;
    if (n >= n_nodes) return;

    float a1[64];
    #pragma unroll
    for (int cc = 0; cc < 4; ++cc) {
        float acc[16];
        #pragma unroll
        for (int j = 0; j < 16; ++j) acc[j] = bm0[cc * 16 + j];
        for (int k = 0; k < 64; ++k) {
            float hv = rows[t][k];
            #pragma unroll
            for (int j = 0; j < 16; ++j)
                acc[j] = fmaf(hv, Wm0[k * 64 + cc * 16 + j], acc[j]);
        }
        #pragma unroll
        for (int j = 0; j < 16; ++j) a1[cc * 16 + j] = fmaxf(acc[j], 0.f);
    }
    #pragma unroll
    for (int k = 0; k < 64; ++k) rows[t][k] = a1[k];

    float a2[32];
    #pragma unroll
    for (int cc = 0; cc < 2; ++cc) {
        float acc[16];
        #pragma unroll
        for (int j = 0; j < 16; ++j) acc[j] = bm1[cc * 16 + j];
        for (int k = 0; k < 64; ++k) {
            float hv = rows[t][k];
            #pragma unroll
            for (int j = 0; j < 16; ++j)
                acc[j] = fmaf(hv, Wm1[k * 32 + cc * 16 + j], acc[j]);
        }
        #pragma unroll
        for (int j = 0; j < 16; ++j) a2[cc * 16 + j] = fmaxf(acc[j], 0.f);
    }
    float z = bm2[0];
    #pragma unroll
    for (int k = 0; k < 32; ++k) z = fmaf(a2[k], Wm2[k], z);
    out[n] = 1.0f / (1.0f + __expf(-z));
}

extern "C" void kernel_launch(void* const* d_in, const int* in_sizes, int n_in,
                              void* d_out, int out_size, void* d_ws, size_t ws_size,
                              hipStream_t stream) {
    const float* x   = (const float*)d_in[0];
    const int*   src = (const int*)d_in[1];
    const int*   dst = (const int*)d_in[2];
    const float* W0  = (const float*)d_in[3];
    const float* b0  = (const float*)d_in[4];
    const float* W1  = (const float*)d_in[5];
    const float* b1  = (const float*)d_in[6];
    const float* g0  = (const float*)d_in[7];
    const float* be0 = (const float*)d_in[8];
    const float* g1  = (const float*)d_in[9];
    const float* be1 = (const float*)d_in[10];
    const float* Wm0 = (const float*)d_in[11];
    const float* bm0 = (const float*)d_in[12];
    const float* Wm1 = (const float*)d_in[13];
    const float* bm1 = (const float*)d_in[14];
    const float* Wm2 = (const float*)d_in[15];
    const float* bm2 = (const float*)d_in[16];

    int n = in_sizes[0] / 4;
    int e = in_sizes[1];
    float* out = (float*)d_out;

    char* ws = (char*)d_ws;
    auto alignup = [](size_t v) { return (v + 255) & ~(size_t)255; };
    size_t o = 0;
    int*   cnt     = (int*)(ws + o);   o += alignup((size_t)n * 4);
    int*   row_ptr = (int*)(ws + o);   o += alignup((size_t)(n + 1) * 4);
    int*   cursor  = (int*)(ws + o);   o += alignup((size_t)n * 4);
    float* dinv    = (float*)(ws + o); o += alignup((size_t)n * 4);
    float* stats   = (float*)(ws + o); o += alignup(256 * 4);
    int*   bsum    = (int*)(ws + o);   o += alignup(256 * 4);
    int*   boff    = (int*)(ws + o);   o += alignup(256 * 4);
    int*   csr     = (int*)(ws + o);   o += alignup((size_t)e * 4);
    float* A       = (float*)(ws + o); o += alignup((size_t)n * 64 * 4);
    float* B       = (float*)(ws + o);

    int gN   = (n + 255) / 256;
    int gE   = (e + 255) / 256;
    int gN4  = (n + 3) / 4;
    int nb   = (n + SCAN_TILE - 1) / SCAN_TILE;     // 98 blocks for n=100k
    int gMLP = (n + 63) / 64;

    hipMemsetAsync(cnt, 0, (size_t)n * 4, stream);
    hipMemsetAsync(stats, 0, 256 * 4, stream);

    // ---- CSR build (once, reused by both layers) ----
    k_hist<<<gE, 256, 0, stream>>>(dst, cnt, e);
    k_scan1<<<nb, 256, 0, stream>>>(cnt, row_ptr, bsum, n);
    k_scan2<<<1, 128, 0, stream>>>(bsum, boff, nb);
    k_scan3<<<gN, 256, 0, stream>>>(row_ptr, cursor, boff, n, e);
    k_dinv<<<gN, 256, 0, stream>>>(cnt, dinv, n);
    k_fill<<<gE, 256, 0, stream>>>(src, dst, cursor, csr, e);

    // ---- layer 1 ----
    k_lin0<<<gN4, 256, 0, stream>>>(x, W0, dinv, A, n);
    k_aggr<<<2048, 256, 0, stream>>>(row_ptr, csr, A, dinv, b0, B, stats, n);

    // ---- layer 2 (BN0+ReLU fused into lin1) ----
    k_lin1<<<2048, 256, 0, stream>>>(B, W1, dinv, stats, g0, be0, A, n);
    k_aggr<<<2048, 256, 0, stream>>>(row_ptr, csr, A, dinv, b1, B, stats + 128, n);

    // ---- MLP head (BN1+ReLU fused) ----
    k_mlp<<<gMLP, 64, 0, stream>>>(B, stats + 128, g1, be1,
                                   Wm0, bm0, Wm1, bm1, Wm2, bm2, out, n);
}

// Round 3
// 529.077 us; speedup vs baseline: 3.3261x; 1.5453x over previous
//
#include <hip/hip_runtime.h>
#include <math.h>

#define HD 64
#define EPS 1e-5f
#define BSH 9                   // bucket shift: 512 nodes per bucket
#define BSZ 512
#define T1 16384                // edges per tile in k_bucket
// packing: n <= 131072 (2^17) required: packed = (local_dst<<17) | src

__device__ __forceinline__ float atomAddF(float* p, float v) {
    return unsafeAtomicAdd(p, v);   // native global_atomic_add_f32 on gfx950
}

// ---------- CSR build (bucketed counting sort) ----------

// per-block LDS bucket histogram -> few global atomics
__global__ __launch_bounds__(256) void k_bhist(const int* __restrict__ dst,
        int* __restrict__ bcnt, int e) {
    __shared__ int h[256];
    int t = threadIdx.x;
    h[t] = 0;
    __syncthreads();
    for (int i = blockIdx.x * 256 + t; i < e; i += gridDim.x * 256)
        atomicAdd(&h[dst[i] >> BSH], 1);
    __syncthreads();
    if (h[t]) atomicAdd(&bcnt[t], h[t]);
}

// single-block scan of bucket counts -> boff (exclusive, boff[nb]=e), gcur
__global__ __launch_bounds__(256) void k_bscan(const int* __restrict__ bcnt,
        int* __restrict__ boff, int* __restrict__ gcur,
        int* __restrict__ row_ptr, int nb, int n, int e) {
    __shared__ int sc[256];
    int t = threadIdx.x;
    int v = (t < nb) ? bcnt[t] : 0;
    sc[t] = v;
    __syncthreads();
    int acc = v;
    for (int off = 1; off < 256; off <<= 1) {
        int x = (t >= off) ? sc[t - off] : 0;
        __syncthreads();
        acc += x;
        sc[t] = acc;
        __syncthreads();
    }
    int ex = acc - v;
    boff[t] = ex;                    // thread nb writes boff[nb] = e
    gcur[t] = ex;
    if (t == 0) row_ptr[n] = e;
}

// pass 1: scatter packed edges into bucket-grouped order
__global__ __launch_bounds__(256) void k_bucket(const int* __restrict__ src,
        const int* __restrict__ dst, int* __restrict__ gcur,
        unsigned* __restrict__ bedges, int e) {
    __shared__ int hist[256];
    __shared__ int base[256];
    int t = threadIdx.x;
    for (int tile = blockIdx.x * T1; tile < e; tile += gridDim.x * T1) {
        int lim = min(e - tile, T1);
        hist[t] = 0;
        __syncthreads();
        for (int j = t; j < lim; j += 256)
            atomicAdd(&hist[dst[tile + j] >> BSH], 1);
        __syncthreads();
        int h = hist[t];
        int mybase = (h > 0) ? atomicAdd(&gcur[t], h) : 0;
        __syncthreads();
        hist[t] = 0;                 // reuse as local cursor
        base[t] = mybase;
        __syncthreads();
        for (int j = t; j < lim; j += 256) {
            int d = dst[tile + j], s = src[tile + j];
            int bk = d >> BSH;
            int loc = atomicAdd(&hist[bk], 1);
            bedges[base[bk] + loc] = ((unsigned)(d & (BSZ - 1)) << 17) | (unsigned)s;
        }
        __syncthreads();
    }
}

// pass 2: one block per bucket -> row_ptr, dinv, csr (sorted by dst)
__global__ __launch_bounds__(256) void k_build(const unsigned* __restrict__ bedges,
        const int* __restrict__ boff, int* __restrict__ row_ptr,
        int* __restrict__ csr, float* __restrict__ dinv, int n) {
    __shared__ int hist[BSZ];
    __shared__ int cur[BSZ];
    __shared__ int sc[256];
    int b = blockIdx.x, t = threadIdx.x;
    int nodebase = b << BSH;
    int beg = boff[b], end = boff[b + 1];
    hist[t] = 0; hist[t + 256] = 0;
    __syncthreads();
    for (int j = beg + t; j < end; j += 256)
        atomicAdd(&hist[bedges[j] >> 17], 1);
    __syncthreads();
    int a0 = hist[2 * t], a1 = hist[2 * t + 1];
    int psum = a0 + a1;
    sc[t] = psum;
    __syncthreads();
    int acc = psum;
    for (int off = 1; off < 256; off <<= 1) {
        int x = (t >= off) ? sc[t - off] : 0;
        __syncthreads();
        acc += x;
        sc[t] = acc;
        __syncthreads();
    }
    int excl = acc - psum;           // exclusive over node pairs
    int e0 = beg + excl, e1 = beg + excl + a0;
    cur[2 * t] = e0;
    cur[2 * t + 1] = e1;
    int n0 = nodebase + 2 * t, n1 = nodebase + 2 * t + 1;
    if (n0 < n) { row_ptr[n0] = e0; dinv[n0] = rsqrtf((float)(a0 + 1)); }
    if (n1 < n) { row_ptr[n1] = e1; dinv[n1] = rsqrtf((float)(a1 + 1)); }
    __syncthreads();
    for (int j = beg + t; j < end; j += 256) {
        unsigned p = bedges[j];
        int pos = atomicAdd(&cur[p >> 17], 1);
        csr[pos] = (int)(p & 0x1FFFFu);
    }
}

// ---------- layer compute ----------
// A[n][c] = dinv[n] * sum_k x[n][k]*W0[k][c]
__global__ __launch_bounds__(256) void k_lin0(const float* __restrict__ x,
        const float* __restrict__ W0, const float* __restrict__ dinv,
        float* __restrict__ A, int n_nodes) {
    __shared__ float w[4 * HD];
    int t = threadIdx.x;
    w[t] = W0[t];
    __syncthreads();
    int n = blockIdx.x * 4 + (t >> 6);
    int c = t & 63;
    if (n >= n_nodes) return;
    float x0 = x[n * 4 + 0], x1 = x[n * 4 + 1], x2 = x[n * 4 + 2], x3 = x[n * 4 + 3];
    float v = x0 * w[c] + x1 * w[64 + c] + x2 * w[128 + c] + x3 * w[192 + c];
    A[n * 64 + c] = v * dinv[n];
}

// CSR gather-aggregate: B[n][c] = dinv[n]*(A[n][c] + sum_in A[src][c]) + bias[c]
// also accumulates per-channel sum/sumsq into stats
__global__ __launch_bounds__(256) void k_aggr(const int* __restrict__ row_ptr,
        const int* __restrict__ csr, const float* __restrict__ A,
        const float* __restrict__ dinv, const float* __restrict__ bias,
        float* __restrict__ B, float* __restrict__ stats, int n_nodes) {
    int t = threadIdx.x;
    int c = t & 63, wv = t >> 6;
    float bc = bias[c];
    float s = 0.f, s2 = 0.f;
    for (int n = blockIdx.x * 4 + wv; n < n_nodes; n += gridDim.x * 4) {
        int beg = row_ptr[n], end = row_ptr[n + 1];
        float acc = A[(n << 6) + c];           // self loop term
        int j = beg;
        for (; j + 3 < end; j += 4) {
            int s0 = csr[j], s1 = csr[j + 1], s2i = csr[j + 2], s3 = csr[j + 3];
            float a0 = A[(s0 << 6) + c];
            float a1 = A[(s1 << 6) + c];
            float a2 = A[(s2i << 6) + c];
            float a3 = A[(s3 << 6) + c];
            acc += a0 + a1 + a2 + a3;
        }
        for (; j < end; ++j) acc += A[(csr[j] << 6) + c];
        float v = dinv[n] * acc + bc;
        B[(n << 6) + c] = v;
        s += v;
        s2 += v * v;
    }
    __shared__ float ls[4][64], ls2[4][64];
    ls[wv][c] = s;
    ls2[wv][c] = s2;
    __syncthreads();
    if (t < 64) {
        float a = ls[0][t] + ls[1][t] + ls[2][t] + ls[3][t];
        float a2 = ls2[0][t] + ls2[1][t] + ls2[2][t] + ls2[3][t];
        atomAddF(&stats[t], a);
        atomAddF(&stats[64 + t], a2);
    }
}

// A <- dinv[n] * (relu(bn(B)) @ W1)     (BN0+ReLU fused into the row staging)
__global__ __launch_bounds__(256) void k_lin1(const float* __restrict__ B,
        const float* __restrict__ W, const float* __restrict__ dinv,
        const float* __restrict__ stats, const float* __restrict__ g,
        const float* __restrict__ be, float* __restrict__ A, int n_nodes) {
    __shared__ float w[HD * HD];
    __shared__ float rows[4][HD];
    int t = threadIdx.x;
    for (int i = t; i < HD * HD; i += 256) w[i] = W[i];
    int wv = t >> 6, c = t & 63;
    float inv_n = 1.0f / (float)n_nodes;
    float mu = stats[c] * inv_n;
    float var = stats[64 + c] * inv_n - mu * mu;
    float sc = g[c] * rsqrtf(var + EPS);
    float sh = be[c] - mu * sc;
    int ngroups = (n_nodes + 3) >> 2;
    for (int gidx = blockIdx.x; gidx < ngroups; gidx += gridDim.x) {
        __syncthreads();
        int n = gidx * 4 + wv;
        float rv = (n < n_nodes) ? fmaxf(sc * B[(n << 6) + c] + sh, 0.f) : 0.f;
        rows[wv][c] = rv;
        __syncthreads();
        if (n < n_nodes) {
            float acc = 0.f;
            #pragma unroll
            for (int k = 0; k < HD; k++) acc = fmaf(rows[wv][k], w[k * 64 + c], acc);
            A[(n << 6) + c] = acc * dinv[n];
        }
    }
}

// fused: h = relu(bn1(B)); out = sigmoid(relu(relu(h@Wm0+bm0)@Wm1+bm1)@Wm2+bm2)
__global__ __launch_bounds__(64) void k_mlp(const float* __restrict__ B,
        const float* __restrict__ stats, const float* __restrict__ g,
        const float* __restrict__ be,
        const float* __restrict__ Wm0, const float* __restrict__ bm0,
        const float* __restrict__ Wm1, const float* __restrict__ bm1,
        const float* __restrict__ Wm2, const float* __restrict__ bm2,
        float* __restrict__ out, int n_nodes) {
    __shared__ float rows[64][65];
    int t = threadIdx.x;
    float inv_n = 1.0f / (float)n_nodes;
    float mu = stats[t] * inv_n;
    float var = stats[64 + t] * inv_n - mu * mu;
    float sc = g[t] * rsqrtf(var + EPS);
    float sh = be[t] - mu * sc;
    int nbase = blockIdx.x * 64;
    #pragma unroll 4
    for (int r = 0; r < 64; r++) {
        int nn = nbase + r;
        rows[r][t] = (nn < n_nodes) ? fmaxf(sc * B[(nn << 6) + t] + sh, 0.f) : 0.f;
    }
    __syncthreads();
    int n = nbase + t;
    if (n >= n_nodes) return;

    float a1[64];
    #pragma unroll
    for (int cc = 0; cc < 4; ++cc) {
        float acc[16];
        #pragma unroll
        for (int j = 0; j < 16; ++j) acc[j] = bm0[cc * 16 + j];
        for (int k = 0; k < 64; ++k) {
            float hv = rows[t][k];
            #pragma unroll
            for (int j = 0; j < 16; ++j)
                acc[j] = fmaf(hv, Wm0[k * 64 + cc * 16 + j], acc[j]);
        }
        #pragma unroll
        for (int j = 0; j < 16; ++j) a1[cc * 16 + j] = fmaxf(acc[j], 0.f);
    }
    #pragma unroll
    for (int k = 0; k < 64; ++k) rows[t][k] = a1[k];

    float a2[32];
    #pragma unroll
    for (int cc = 0; cc < 2; ++cc) {
        float acc[16];
        #pragma unroll
        for (int j = 0; j < 16; ++j) acc[j] = bm1[cc * 16 + j];
        for (int k = 0; k < 64; ++k) {
            float hv = rows[t][k];
            #pragma unroll
            for (int j = 0; j < 16; ++j)
                acc[j] = fmaf(hv, Wm1[k * 32 + cc * 16 + j], acc[j]);
        }
        #pragma unroll
        for (int j = 0; j < 16; ++j) a2[cc * 16 + j] = fmaxf(acc[j], 0.f);
    }
    float z = bm2[0];
    #pragma unroll
    for (int k = 0; k < 32; ++k) z = fmaf(a2[k], Wm2[k], z);
    out[n] = 1.0f / (1.0f + __expf(-z));
}

extern "C" void kernel_launch(void* const* d_in, const int* in_sizes, int n_in,
                              void* d_out, int out_size, void* d_ws, size_t ws_size,
                              hipStream_t stream) {
    const float* x   = (const float*)d_in[0];
    const int*   src = (const int*)d_in[1];
    const int*   dst = (const int*)d_in[2];
    const float* W0  = (const float*)d_in[3];
    const float* b0  = (const float*)d_in[4];
    const float* W1  = (const float*)d_in[5];
    const float* b1  = (const float*)d_in[6];
    const float* g0  = (const float*)d_in[7];
    const float* be0 = (const float*)d_in[8];
    const float* g1  = (const float*)d_in[9];
    const float* be1 = (const float*)d_in[10];
    const float* Wm0 = (const float*)d_in[11];
    const float* bm0 = (const float*)d_in[12];
    const float* Wm1 = (const float*)d_in[13];
    const float* bm1 = (const float*)d_in[14];
    const float* Wm2 = (const float*)d_in[15];
    const float* bm2 = (const float*)d_in[16];

    int n = in_sizes[0] / 4;
    int e = in_sizes[1];
    float* out = (float*)d_out;

    char* ws = (char*)d_ws;
    auto alignup = [](size_t v) { return (v + 255) & ~(size_t)255; };
    size_t o = 0;
    int*      bcnt    = (int*)(ws + o);      o += alignup(256 * 4);
    int*      boff    = (int*)(ws + o);      o += alignup(257 * 4);
    int*      gcur    = (int*)(ws + o);      o += alignup(256 * 4);
    float*    stats   = (float*)(ws + o);    o += alignup(256 * 4);
    int*      row_ptr = (int*)(ws + o);      o += alignup((size_t)(n + 1) * 4);
    float*    dinv    = (float*)(ws + o);    o += alignup((size_t)n * 4);
    unsigned* bedges  = (unsigned*)(ws + o); o += alignup((size_t)e * 4);
    int*      csr     = (int*)(ws + o);      o += alignup((size_t)e * 4);
    float*    A       = (float*)(ws + o);    o += alignup((size_t)n * 64 * 4);
    float*    B       = (float*)(ws + o);

    int nb     = (n + BSZ - 1) >> BSH;        // 196 buckets for n=100k (requires n<=131072)
    int gN4    = (n + 3) / 4;
    int ntiles = (e + T1 - 1) / T1;
    int gMLP   = (n + 63) / 64;

    hipMemsetAsync(bcnt, 0, 256 * 4, stream);
    hipMemsetAsync(stats, 0, 256 * 4, stream);

    // ---- CSR build (bucketed, once, reused by both layers) ----
    k_bhist<<<512, 256, 0, stream>>>(dst, bcnt, e);
    k_bscan<<<1, 256, 0, stream>>>(bcnt, boff, gcur, row_ptr, nb, n, e);
    k_bucket<<<ntiles, 256, 0, stream>>>(src, dst, gcur, bedges, e);
    k_build<<<nb, 256, 0, stream>>>(bedges, boff, row_ptr, csr, dinv, n);

    // ---- layer 1 ----
    k_lin0<<<gN4, 256, 0, stream>>>(x, W0, dinv, A, n);
    k_aggr<<<2048, 256, 0, stream>>>(row_ptr, csr, A, dinv, b0, B, stats, n);

    // ---- layer 2 (BN0+ReLU fused into lin1) ----
    k_lin1<<<2048, 256, 0, stream>>>(B, W1, dinv, stats, g0, be0, A, n);
    k_aggr<<<2048, 256, 0, stream>>>(row_ptr, csr, A, dinv, b1, B, stats + 128, n);

    // ---- MLP head (BN1+ReLU fused) ----
    k_mlp<<<gMLP, 64, 0, stream>>>(B, stats + 128, g1, be1,
                                   Wm0, bm0, Wm1, bm1, Wm2, bm2, out, n);
}

// Round 4
// 456.524 us; speedup vs baseline: 3.8547x; 1.1589x over previous
//
#include <hip/hip_runtime.h>
#include <hip/hip_fp16.h>
#include <math.h>

#define HD 64
#define EPS 1e-5f
#define BSH 9                   // bucket shift: 512 nodes per bucket
#define BSZ 512
#define T1 16384                // edges per tile in k_bucket
// packing: n <= 131072 (2^17) required: packed = (local_dst<<17) | src

__device__ __forceinline__ float atomAddF(float* p, float v) {
    return unsafeAtomicAdd(p, v);   // native global_atomic_add_f32 on gfx950
}

__device__ __forceinline__ void h8_to_f(const uint4 u, float* f) {
    const __half2* h = reinterpret_cast<const __half2*>(&u);
    #pragma unroll
    for (int i = 0; i < 4; ++i) {
        float2 p = __half22float2(h[i]);
        f[2 * i] = p.x; f[2 * i + 1] = p.y;
    }
}

// ---------- CSR build (bucketed counting sort) ----------

__global__ __launch_bounds__(256) void k_bhist(const int* __restrict__ dst,
        int* __restrict__ bcnt, int e) {
    __shared__ int h[256];
    int t = threadIdx.x;
    h[t] = 0;
    __syncthreads();
    for (int i = blockIdx.x * 256 + t; i < e; i += gridDim.x * 256)
        atomicAdd(&h[dst[i] >> BSH], 1);
    __syncthreads();
    if (h[t]) atomicAdd(&bcnt[t], h[t]);
}

__global__ __launch_bounds__(256) void k_bscan(const int* __restrict__ bcnt,
        int* __restrict__ boff, int* __restrict__ gcur,
        int* __restrict__ row_ptr, int nb, int n, int e) {
    __shared__ int sc[256];
    int t = threadIdx.x;
    int v = (t < nb) ? bcnt[t] : 0;
    sc[t] = v;
    __syncthreads();
    int acc = v;
    for (int off = 1; off < 256; off <<= 1) {
        int x = (t >= off) ? sc[t - off] : 0;
        __syncthreads();
        acc += x;
        sc[t] = acc;
        __syncthreads();
    }
    int ex = acc - v;
    boff[t] = ex;                    // thread nb writes boff[nb] = e
    gcur[t] = ex;
    if (t == 0) row_ptr[n] = e;
}

__global__ __launch_bounds__(256) void k_bucket(const int* __restrict__ src,
        const int* __restrict__ dst, int* __restrict__ gcur,
        unsigned* __restrict__ bedges, int e) {
    __shared__ int hist[256];
    __shared__ int base[256];
    int t = threadIdx.x;
    for (int tile = blockIdx.x * T1; tile < e; tile += gridDim.x * T1) {
        int lim = min(e - tile, T1);
        hist[t] = 0;
        __syncthreads();
        for (int j = t; j < lim; j += 256)
            atomicAdd(&hist[dst[tile + j] >> BSH], 1);
        __syncthreads();
        int h = hist[t];
        int mybase = (h > 0) ? atomicAdd(&gcur[t], h) : 0;
        __syncthreads();
        hist[t] = 0;                 // reuse as local cursor
        base[t] = mybase;
        __syncthreads();
        for (int j = t; j < lim; j += 256) {
            int d = dst[tile + j], s = src[tile + j];
            int bk = d >> BSH;
            int loc = atomicAdd(&hist[bk], 1);
            bedges[base[bk] + loc] = ((unsigned)(d & (BSZ - 1)) << 17) | (unsigned)s;
        }
        __syncthreads();
    }
}

__global__ __launch_bounds__(256) void k_build(const unsigned* __restrict__ bedges,
        const int* __restrict__ boff, int* __restrict__ row_ptr,
        int* __restrict__ csr, float* __restrict__ dinv, int n) {
    __shared__ int hist[BSZ];
    __shared__ int cur[BSZ];
    __shared__ int sc[256];
    int b = blockIdx.x, t = threadIdx.x;
    int nodebase = b << BSH;
    int beg = boff[b], end = boff[b + 1];
    hist[t] = 0; hist[t + 256] = 0;
    __syncthreads();
    for (int j = beg + t; j < end; j += 256)
        atomicAdd(&hist[bedges[j] >> 17], 1);
    __syncthreads();
    int a0 = hist[2 * t], a1 = hist[2 * t + 1];
    int psum = a0 + a1;
    sc[t] = psum;
    __syncthreads();
    int acc = psum;
    for (int off = 1; off < 256; off <<= 1) {
        int x = (t >= off) ? sc[t - off] : 0;
        __syncthreads();
        acc += x;
        sc[t] = acc;
        __syncthreads();
    }
    int excl = acc - psum;           // exclusive over node pairs
    int e0 = beg + excl, e1 = beg + excl + a0;
    cur[2 * t] = e0;
    cur[2 * t + 1] = e1;
    int n0 = nodebase + 2 * t, n1 = nodebase + 2 * t + 1;
    if (n0 < n) { row_ptr[n0] = e0; dinv[n0] = rsqrtf((float)(a0 + 1)); }
    if (n1 < n) { row_ptr[n1] = e1; dinv[n1] = rsqrtf((float)(a1 + 1)); }
    __syncthreads();
    for (int j = beg + t; j < end; j += 256) {
        unsigned p = bedges[j];
        int pos = atomicAdd(&cur[p >> 17], 1);
        csr[pos] = (int)(p & 0x1FFFFu);
    }
}

// ---------- layer compute ----------
// A[n][c] = half( dinv[n] * sum_k x[n][k]*W0[k][c] )
__global__ __launch_bounds__(256) void k_lin0(const float* __restrict__ x,
        const float* __restrict__ W0, const float* __restrict__ dinv,
        __half* __restrict__ A, int n_nodes) {
    __shared__ float w[4 * HD];
    int t = threadIdx.x;
    w[t] = W0[t];
    __syncthreads();
    int n = blockIdx.x * 4 + (t >> 6);
    int c = t & 63;
    if (n >= n_nodes) return;
    float x0 = x[n * 4 + 0], x1 = x[n * 4 + 1], x2 = x[n * 4 + 2], x3 = x[n * 4 + 3];
    float v = x0 * w[c] + x1 * w[64 + c] + x2 * w[128 + c] + x3 * w[192 + c];
    A[(n << 6) + c] = __float2half(v * dinv[n]);
}

// CSR gather-aggregate (fp16 source, 16B/lane, 8 edges per wave-instr):
// B[n][c] = dinv[n]*(A[n][c] + sum_in A[src][c]) + bias[c]; stats accumulated
__global__ __launch_bounds__(256) void k_aggr(const int* __restrict__ row_ptr,
        const int* __restrict__ csr, const __half* __restrict__ A,
        const float* __restrict__ dinv, const float* __restrict__ bias,
        float* __restrict__ B, float* __restrict__ stats, int n_nodes) {
    int t = threadIdx.x;
    int lane = t & 63, wv = t >> 6;
    int eg = lane >> 3, cg = lane & 7;     // edge slot 0..7, channel group 0..7
    float st[8], st2[8];
    #pragma unroll
    for (int k = 0; k < 8; ++k) { st[k] = 0.f; st2[k] = 0.f; }
    for (int n = blockIdx.x * 4 + wv; n < n_nodes; n += gridDim.x * 4) {
        int beg = row_ptr[n], end = row_ptr[n + 1];
        float acc[8];
        {   // self-loop term (only eg==0 keeps it; load is broadcast-dedup'd)
            uint4 u = *reinterpret_cast<const uint4*>(A + ((size_t)n << 6) + (cg << 3));
            float f[8]; h8_to_f(u, f);
            float m = (eg == 0) ? 1.f : 0.f;
            #pragma unroll
            for (int k = 0; k < 8; ++k) acc[k] = m * f[k];
        }
        int j = beg;
        for (; j + 16 <= end; j += 16) {   // 2 independent gathers in flight
            int s0 = csr[j + eg];
            int s1 = csr[j + 8 + eg];
            uint4 u0 = *reinterpret_cast<const uint4*>(A + ((size_t)s0 << 6) + (cg << 3));
            uint4 u1 = *reinterpret_cast<const uint4*>(A + ((size_t)s1 << 6) + (cg << 3));
            float f0[8], f1[8];
            h8_to_f(u0, f0); h8_to_f(u1, f1);
            #pragma unroll
            for (int k = 0; k < 8; ++k) acc[k] += f0[k] + f1[k];
        }
        for (; j < end; j += 8) {
            int idx = j + eg;
            if (idx < end) {
                int s = csr[idx];
                uint4 u = *reinterpret_cast<const uint4*>(A + ((size_t)s << 6) + (cg << 3));
                float f[8]; h8_to_f(u, f);
                #pragma unroll
                for (int k = 0; k < 8; ++k) acc[k] += f[k];
            }
        }
        // reduce over edge slots: eg bits are lane bits 3,4,5
        #pragma unroll
        for (int d = 8; d < 64; d <<= 1) {
            #pragma unroll
            for (int k = 0; k < 8; ++k) acc[k] += __shfl_xor(acc[k], d, 64);
        }
        if (eg == 0) {
            float dv = dinv[n];
            float v[8];
            #pragma unroll
            for (int k = 0; k < 8; ++k) {
                v[k] = dv * acc[k] + bias[(cg << 3) + k];
                st[k] += v[k]; st2[k] += v[k] * v[k];
            }
            float4* bp = reinterpret_cast<float4*>(B + ((size_t)n << 6) + (cg << 3));
            bp[0] = make_float4(v[0], v[1], v[2], v[3]);
            bp[1] = make_float4(v[4], v[5], v[6], v[7]);
        }
    }
    __shared__ float ls[4][64], ls2[4][64];
    if (eg == 0) {
        #pragma unroll
        for (int k = 0; k < 8; ++k) {
            ls[wv][(cg << 3) + k] = st[k];
            ls2[wv][(cg << 3) + k] = st2[k];
        }
    }
    __syncthreads();
    if (t < 64) {
        float a = ls[0][t] + ls[1][t] + ls[2][t] + ls[3][t];
        float a2 = ls2[0][t] + ls2[1][t] + ls2[2][t] + ls2[3][t];
        atomAddF(&stats[t], a);
        atomAddF(&stats[64 + t], a2);
    }
}

// A(half) <- dinv[n] * (relu(bn(B)) @ W1)     (BN0+ReLU fused into row staging)
__global__ __launch_bounds__(256) void k_lin1(const float* __restrict__ B,
        const float* __restrict__ W, const float* __restrict__ dinv,
        const float* __restrict__ stats, const float* __restrict__ g,
        const float* __restrict__ be, __half* __restrict__ A, int n_nodes) {
    __shared__ float w[HD * HD];
    __shared__ float rows[4][HD];
    int t = threadIdx.x;
    for (int i = t; i < HD * HD; i += 256) w[i] = W[i];
    int wv = t >> 6, c = t & 63;
    float inv_n = 1.0f / (float)n_nodes;
    float mu = stats[c] * inv_n;
    float var = stats[64 + c] * inv_n - mu * mu;
    float sc = g[c] * rsqrtf(var + EPS);
    float sh = be[c] - mu * sc;
    int ngroups = (n_nodes + 3) >> 2;
    for (int gidx = blockIdx.x; gidx < ngroups; gidx += gridDim.x) {
        __syncthreads();
        int n = gidx * 4 + wv;
        float rv = (n < n_nodes) ? fmaxf(sc * B[(n << 6) + c] + sh, 0.f) : 0.f;
        rows[wv][c] = rv;
        __syncthreads();
        if (n < n_nodes) {
            float acc = 0.f;
            #pragma unroll
            for (int k = 0; k < HD; k++) acc = fmaf(rows[wv][k], w[k * 64 + c], acc);
            A[(n << 6) + c] = __float2half(acc * dinv[n]);
        }
    }
}

// fused: h = relu(bn1(B)); out = sigmoid(relu(relu(h@Wm0+bm0)@Wm1+bm1)@Wm2+bm2)
__global__ __launch_bounds__(64) void k_mlp(const float* __restrict__ B,
        const float* __restrict__ stats, const float* __restrict__ g,
        const float* __restrict__ be,
        const float* __restrict__ Wm0, const float* __restrict__ bm0,
        const float* __restrict__ Wm1, const float* __restrict__ bm1,
        const float* __restrict__ Wm2, const float* __restrict__ bm2,
        float* __restrict__ out, int n_nodes) {
    __shared__ float rows[64][65];
    int t = threadIdx.x;
    float inv_n = 1.0f / (float)n_nodes;
    float mu = stats[t] * inv_n;
    float var = stats[64 + t] * inv_n - mu * mu;
    float sc = g[t] * rsqrtf(var + EPS);
    float sh = be[t] - mu * sc;
    int nbase = blockIdx.x * 64;
    #pragma unroll 4
    for (int r = 0; r < 64; r++) {
        int nn = nbase + r;
        rows[r][t] = (nn < n_nodes) ? fmaxf(sc * B[(nn << 6) + t] + sh, 0.f) : 0.f;
    }
    __syncthreads();
    int n = nbase + t;
    if (n >= n_nodes) return;

    float a1[64];
    #pragma unroll
    for (int cc = 0; cc < 4; ++cc) {
        float acc[16];
        #pragma unroll
        for (int j = 0; j < 16; ++j) acc[j] = bm0[cc * 16 + j];
        for (int k = 0; k < 64; ++k) {
            float hv = rows[t][k];
            #pragma unroll
            for (int j = 0; j < 16; ++j)
                acc[j] = fmaf(hv, Wm0[k * 64 + cc * 16 + j], acc[j]);
        }
        #pragma unroll
        for (int j = 0; j < 16; ++j) a1[cc * 16 + j] = fmaxf(acc[j], 0.f);
    }
    #pragma unroll
    for (int k = 0; k < 64; ++k) rows[t][k] = a1[k];

    float a2[32];
    #pragma unroll
    for (int cc = 0; cc < 2; ++cc) {
        float acc[16];
        #pragma unroll
        for (int j = 0; j < 16; ++j) acc[j] = bm1[cc * 16 + j];
        for (int k = 0; k < 64; ++k) {
            float hv = rows[t][k];
            #pragma unroll
            for (int j = 0; j < 16; ++j)
                acc[j] = fmaf(hv, Wm1[k * 32 + cc * 16 + j], acc[j]);
        }
        #pragma unroll
        for (int j = 0; j < 16; ++j) a2[cc * 16 + j] = fmaxf(acc[j], 0.f);
    }
    float z = bm2[0];
    #pragma unroll
    for (int k = 0; k < 32; ++k) z = fmaf(a2[k], Wm2[k], z);
    out[n] = 1.0f / (1.0f + __expf(-z));
}

extern "C" void kernel_launch(void* const* d_in, const int* in_sizes, int n_in,
                              void* d_out, int out_size, void* d_ws, size_t ws_size,
                              hipStream_t stream) {
    const float* x   = (const float*)d_in[0];
    const int*   src = (const int*)d_in[1];
    const int*   dst = (const int*)d_in[2];
    const float* W0  = (const float*)d_in[3];
    const float* b0  = (const float*)d_in[4];
    const float* W1  = (const float*)d_in[5];
    const float* b1  = (const float*)d_in[6];
    const float* g0  = (const float*)d_in[7];
    const float* be0 = (const float*)d_in[8];
    const float* g1  = (const float*)d_in[9];
    const float* be1 = (const float*)d_in[10];
    const float* Wm0 = (const float*)d_in[11];
    const float* bm0 = (const float*)d_in[12];
    const float* Wm1 = (const float*)d_in[13];
    const float* bm1 = (const float*)d_in[14];
    const float* Wm2 = (const float*)d_in[15];
    const float* bm2 = (const float*)d_in[16];

    int n = in_sizes[0] / 4;
    int e = in_sizes[1];
    float* out = (float*)d_out;

    char* ws = (char*)d_ws;
    auto alignup = [](size_t v) { return (v + 255) & ~(size_t)255; };
    size_t o = 0;
    int*      bcnt    = (int*)(ws + o);      o += alignup(256 * 4);
    int*      boff    = (int*)(ws + o);      o += alignup(257 * 4);
    int*      gcur    = (int*)(ws + o);      o += alignup(256 * 4);
    float*    stats   = (float*)(ws + o);    o += alignup(256 * 4);
    int*      row_ptr = (int*)(ws + o);      o += alignup((size_t)(n + 1) * 4);
    float*    dinv    = (float*)(ws + o);    o += alignup((size_t)n * 4);
    unsigned* bedges  = (unsigned*)(ws + o); o += alignup((size_t)e * 4);
    int*      csr     = (int*)(ws + o);      o += alignup((size_t)e * 4);
    __half*   A       = (__half*)(ws + o);   o += alignup((size_t)n * 64 * 2);
    float*    B       = (float*)(ws + o);

    int nb     = (n + BSZ - 1) >> BSH;        // 196 buckets for n=100k (requires n<=131072)
    int gN4    = (n + 3) / 4;
    int ntiles = (e + T1 - 1) / T1;
    int gMLP   = (n + 63) / 64;

    hipMemsetAsync(bcnt, 0, 256 * 4, stream);
    hipMemsetAsync(stats, 0, 256 * 4, stream);

    // ---- CSR build (bucketed, once, reused by both layers) ----
    k_bhist<<<512, 256, 0, stream>>>(dst, bcnt, e);
    k_bscan<<<1, 256, 0, stream>>>(bcnt, boff, gcur, row_ptr, nb, n, e);
    k_bucket<<<ntiles, 256, 0, stream>>>(src, dst, gcur, bedges, e);
    k_build<<<nb, 256, 0, stream>>>(bedges, boff, row_ptr, csr, dinv, n);

    // ---- layer 1 ----
    k_lin0<<<gN4, 256, 0, stream>>>(x, W0, dinv, A, n);
    k_aggr<<<2048, 256, 0, stream>>>(row_ptr, csr, A, dinv, b0, B, stats, n);

    // ---- layer 2 (BN0+ReLU fused into lin1) ----
    k_lin1<<<2048, 256, 0, stream>>>(B, W1, dinv, stats, g0, be0, A, n);
    k_aggr<<<2048, 256, 0, stream>>>(row_ptr, csr, A, dinv, b1, B, stats + 128, n);

    // ---- MLP head (BN1+ReLU fused) ----
    k_mlp<<<gMLP, 64, 0, stream>>>(B, stats + 128, g1, be1,
                                   Wm0, bm0, Wm1, bm1, Wm2, bm2, out, n);
}